// Round 7
// baseline (451.841 us; speedup 1.0000x reference)
//
#include <hip/hip_runtime.h>

// Resample2d (Flownet2-style) bilinear warp.
// feature: [B,C,H,W] fp32, flow: [B,2,H,W] fp32, out: [B,C,H,W] fp32.
//
// R8: shrink the scheduling quantum so phases actually overlap. R4-R7 all
// converged to ~165-170us with every pipe <35% busy because 1024-thread
// blocks never truly co-resided (Occupancy 43-45% across R5/R7) -> the
// serial STAGE->barrier->COMPUTE chain ran unoverlapped. Changes:
//  - 512-thread blocks, 32x32 tiles, window 57x59 float2 = 26.9KB LDS ->
//    4 blocks/CU (32 waves). Four independently-phased blocks per CU keep
//    LDS/VALU/VMEM pipes fed while any one block drains or barriers.
//  - Keep R5's amortization (the VALU 104k->62k cyc win): flow, weights,
//    gather addrs computed once for all GPB=4 groups; staging addresses
//    gOff[7] computed once per block; stage loads prefetched before the
//    previous group's COMPUTE.
//  - Register diet to stay <=64 VGPR naturally (no forced bounds - R6
//    lesson): vbits/iw bitmasks, recomputed site indices, KITERS=2.
//  - Keep: CPB=2 float2 sites, odd SW=59, rare global fallback,
//    nontemporal stores, bijective XCD swizzle (7168 % 8 == 0).

#define Bv 2
#define Cv 64
#define Hv 512
#define Wv 896
#define HWsz (Hv * Wv)

#define TILEX 32
#define TILEY 32
#define CPB 2                    // channels per LDS site (float2)
#define GPB 4                    // channel-groups per block -> 8 channels
#define NCG (Cv / CPB)           // 32
#define NCGB (NCG / GPB)         // 8 group-batches
#define SW 59                    // staged cols; ODD -> bank mixing
#define SH 57                    // staged rows
#define XOFF 12                  // xs = tx0 - 12 ; x0 <= tx0+45 covered
#define YOFF 11                  // ys = ty0 - 11 ; y0 <= ty0+44 covered
#define NSITES (SH * SW)         // 3363 -> 26,904 B LDS
#define NTX (Wv / TILEX)         // 28
#define NTY (Hv / TILEY)         // 16
#define NTILES (NTX * NTY)       // 448
#define NBLK (Bv * NCGB * NTILES)  // 7168, %8==0
#define THREADS 512
#define KITERS (TILEX * TILEY / THREADS)        // 2 pixel-iters/thread
#define SITE_ITERS ((NSITES + THREADS - 1) / THREADS)  // 7

__global__ __launch_bounds__(THREADS) void resample2d_kernel(
    const float* __restrict__ feature,
    const float* __restrict__ flow,
    float* __restrict__ out) {
    __shared__ float2 smem[NSITES];  // 26,904 B -> 4 blocks/CU

    // Bijective XCD-chunked swizzle: consecutive wids are adjacent x-tiles of
    // the same channel batch -> halo re-reads are same-XCD L2 hits.
    const int orig = blockIdx.x;
    const int wid = (orig & 7) * (NBLK / 8) + (orig >> 3);
    const int txi = wid % NTX;
    const int t2 = wid / NTX;
    const int tyi = t2 % NTY;
    const int zb = t2 / NTY;        // (b, group-batch)
    const int b = zb / NCGB;
    const int c0 = (zb % NCGB) * (GPB * CPB);

    const int tx0 = txi * TILEX;
    const int ty0 = tyi * TILEY;
    const int xs = tx0 - XOFF;
    const int ys = ty0 - YOFF;

    const int tid = threadIdx.x;

    const float* __restrict__ fbase = feature + ((size_t)b * Cv + c0) * HWsz;
    const float* __restrict__ flb = flow + (size_t)b * 2 * HWsz;
    float* __restrict__ ob = out + ((size_t)b * Cv + c0) * HWsz;

    // ---- A: flow loads (issued first; latency hides under site precompute)
    float u[KITERS], v[KITERS];
#pragma unroll
    for (int k = 0; k < KITERS; ++k) {
        const int q = tid + THREADS * k;          // 0..1023
        const int pix = (ty0 + (q >> 5)) * Wv + tx0 + (q & 31);
        u[k] = flb[pix];
        v[k] = flb[HWsz + pix];
    }

    // ---- Staging-site precompute (ONCE; reused for all 4 groups).
    // p >= NSITES lanes clamp to last site (duplicate identical writes).
    int gOff[SITE_ITERS];
    unsigned vbits = 0;
#pragma unroll
    for (int i = 0; i < SITE_ITERS; ++i) {
        const int p = tid + THREADS * i;
        const int pc = (p < NSITES) ? p : (NSITES - 1);
        const int r = pc / SW;
        const int xx = pc - r * SW;
        const int gy = ys + r;
        const int gx = xs + xx;
        const bool vd = ((unsigned)gy < (unsigned)Hv) & ((unsigned)gx < (unsigned)Wv);
        gOff[i] = vd ? (gy * Wv + gx) : 0;
        vbits |= vd ? (1u << i) : 0u;
    }

#define STAGE_LOAD(G)                                            \
    do {                                                         \
        const float* __restrict__ fg_ =                          \
            fbase + (size_t)(G) * CPB * HWsz;                    \
        _Pragma("unroll") for (int i = 0; i < SITE_ITERS; ++i) { \
            a0[i] = fg_[gOff[i]];                                \
            a1[i] = fg_[gOff[i] + HWsz];                         \
        }                                                        \
    } while (0)

#define STAGE_WRITE()                                                     \
    do {                                                                  \
        _Pragma("unroll") for (int i = 0; i < SITE_ITERS; ++i) {          \
            const int p_ = tid + THREADS * i;                             \
            const int pc_ = (p_ < NSITES) ? p_ : (NSITES - 1);            \
            const float m_ = (vbits & (1u << i)) ? 1.0f : 0.0f;           \
            smem[pc_] = make_float2(a0[i] * m_, a1[i] * m_);              \
        }                                                                 \
    } while (0)

    float a0[SITE_ITERS], a1[SITE_ITERS];
    STAGE_LOAD(0);

    // ---- Weights + clamped LDS site addresses (ONCE; reused x4 groups).
    float w00k[KITERS], w10k[KITERS], w01k[KITERS], w11k[KITERS];
    int ac[KITERS];
    unsigned iw = 0;
#pragma unroll
    for (int k = 0; k < KITERS; ++k) {
        const int q = tid + THREADS * k;
        const int px = tx0 + (q & 31);
        const int y = ty0 + (q >> 5);
        const float gx = u[k] + (float)px;
        const float gy = v[k] + (float)y;
        const float x0f = floorf(gx);
        const float y0f = floorf(gy);
        const float wx = gx - x0f;
        const float wy = gy - y0f;
        const float omx = 1.0f - wx;
        const float omy = 1.0f - wy;
        w00k[k] = omx * omy;
        w10k[k] = wx * omy;
        w01k[k] = omx * wy;
        w11k[k] = wx * wy;
        const int lx = (int)x0f - xs;
        const int ly = (int)y0f - ys;
        const bool inwin = ((unsigned)lx <= (unsigned)(SW - 2)) &
                           ((unsigned)ly <= (unsigned)(SH - 2));
        iw |= inwin ? (1u << k) : 0u;
        const int lxc = min(max(lx, 0), SW - 2);
        const int lyc = min(max(ly, 0), SH - 2);
        ac[k] = lyc * SW + lxc;
    }

#define COMPUTE(G)                                                             \
    do {                                                                       \
        float* __restrict__ og_ = ob + (size_t)(G) * CPB * HWsz;               \
        const float* __restrict__ fg_ = fbase + (size_t)(G) * CPB * HWsz;      \
        _Pragma("unroll") for (int k = 0; k < KITERS; ++k) {                   \
            const int q_ = tid + THREADS * k;                                  \
            const int px_ = tx0 + (q_ & 31);                                   \
            const int y_ = ty0 + (q_ >> 5);                                    \
            float2 t00 = smem[ac[k]];                                          \
            float2 t10 = smem[ac[k] + 1];                                      \
            float2 t01 = smem[ac[k] + SW];                                     \
            float2 t11 = smem[ac[k] + SW + 1];                                 \
            if (!(iw & (1u << k))) { /* rare Gaussian-tail fallback */         \
                const float gx_ = u[k] + (float)px_;                           \
                const float gy_ = v[k] + (float)y_;                            \
                const int x0_ = (int)floorf(gx_);                              \
                const int y0_ = (int)floorf(gy_);                              \
                const int x1_ = x0_ + 1, y1_ = y0_ + 1;                        \
                const bool vx0 = (unsigned)x0_ < (unsigned)Wv;                 \
                const bool vx1 = (unsigned)x1_ < (unsigned)Wv;                 \
                const bool vy0 = (unsigned)y0_ < (unsigned)Hv;                 \
                const bool vy1 = (unsigned)y1_ < (unsigned)Hv;                 \
                const int cx0 = min(max(x0_, 0), Wv - 1);                      \
                const int cx1 = min(max(x1_, 0), Wv - 1);                      \
                const int cy0 = min(max(y0_, 0), Hv - 1);                      \
                const int cy1 = min(max(y1_, 0), Hv - 1);                      \
                _Pragma("unroll") for (int c = 0; c < CPB; ++c) {              \
                    const float* f = fg_ + (size_t)c * HWsz;                   \
                    ((float*)&t00)[c] = (vx0 & vy0) ? f[cy0 * Wv + cx0] : 0.f; \
                    ((float*)&t10)[c] = (vx1 & vy0) ? f[cy0 * Wv + cx1] : 0.f; \
                    ((float*)&t01)[c] = (vx0 & vy1) ? f[cy1 * Wv + cx0] : 0.f; \
                    ((float*)&t11)[c] = (vx1 & vy1) ? f[cy1 * Wv + cx1] : 0.f; \
                }                                                              \
            }                                                                  \
            const float r0 = t00.x * w00k[k] + t10.x * w10k[k] +               \
                             t01.x * w01k[k] + t11.x * w11k[k];                \
            const float r1 = t00.y * w00k[k] + t10.y * w10k[k] +               \
                             t01.y * w01k[k] + t11.y * w11k[k];                \
            const int pix_ = y_ * Wv + px_;                                    \
            __builtin_nontemporal_store(r0, &og_[pix_]);                       \
            __builtin_nontemporal_store(r1, &og_[HWsz + pix_]);                \
        }                                                                      \
    } while (0)

    // ---- Group loop: loads(g+1) issued before COMPUTE(g); single buffer,
    // two barriers per group. 4 co-resident blocks/CU cover the bubbles.
    STAGE_WRITE();
    __syncthreads();

    STAGE_LOAD(1);
    COMPUTE(0);
    __syncthreads();
    STAGE_WRITE();
    __syncthreads();

    STAGE_LOAD(2);
    COMPUTE(1);
    __syncthreads();
    STAGE_WRITE();
    __syncthreads();

    STAGE_LOAD(3);
    COMPUTE(2);
    __syncthreads();
    STAGE_WRITE();
    __syncthreads();

    COMPUTE(3);

#undef STAGE_LOAD
#undef STAGE_WRITE
#undef COMPUTE
}

extern "C" void kernel_launch(void* const* d_in, const int* in_sizes, int n_in,
                              void* d_out, int out_size, void* d_ws, size_t ws_size,
                              hipStream_t stream) {
    const float* feature = (const float*)d_in[0];
    const float* flow = (const float*)d_in[1];
    float* out = (float*)d_out;

    dim3 block(THREADS, 1, 1);
    dim3 grid(NBLK, 1, 1);
    resample2d_kernel<<<grid, block, 0, stream>>>(feature, flow, out);
}